// Round 4
// baseline (431.122 us; speedup 1.0000x reference)
//
#include <hip/hip_runtime.h>
#include <stdint.h>

// Problem constants: B=16, C=48, H=W=64, N_CORR=2048
#define BB 16
#define HW 4096
#define NC 2048
#define KHW 72           // halfwords per column: 48 data + 16 zeros (K-pad to 64) + 8 pad
#define KB 144           // bytes per column (16B-aligned)

typedef __attribute__((ext_vector_type(8))) __bf16 bf16x8;
typedef __attribute__((ext_vector_type(8))) short short8;
typedef __attribute__((ext_vector_type(4))) float floatx4;

static __device__ __forceinline__ unsigned short f2bf(float f) {
    unsigned u = __builtin_bit_cast(unsigned, f);
    unsigned r = u + 0x7fffu + ((u >> 16) & 1u);    // RNE
    return (unsigned short)(r >> 16);
}

#define GLD16(g, l) __builtin_amdgcn_global_load_lds((const __attribute__((address_space(1))) void*)(g), (__attribute__((address_space(3))) void*)(l), 16, 0, 0)
#define GLD4(g, l)  __builtin_amdgcn_global_load_lds((const __attribute__((address_space(1))) void*)(g), (__attribute__((address_space(3))) void*)(l), 4, 0, 0)

// ---------------------------------------------------------------------------
// prep_fused: three independent jobs in one launch (all feed maxscore):
//   blocks [0,512):   normalize x1,x2 columns -> bf16 dbp (K-padded, 144B)
//   blocks [512,544): counting sort of each (dir,b) query segment by qi
//   blocks [544,552): zero maxs2enc (atomicMax identity)
// ---------------------------------------------------------------------------
__global__ void prep_fused(const float* __restrict__ x1, const float* __restrict__ x2,
                           const int* __restrict__ ids, const int* __restrict__ fp2,
                           unsigned short* __restrict__ dbp,
                           int* __restrict__ perm, int* __restrict__ qcol_s,
                           int* __restrict__ aqpack, unsigned int* __restrict__ maxs2enc) {
    int bid = blockIdx.x, tid = threadIdx.x;
    __shared__ int hist[64], base[64];
    if (bid < 512) {
        int gid = bid * 256 + tid;                // [0, 2*16*4096)
        int img = gid >> 16;
        int rem = gid & 65535;
        int b = rem >> 12;
        int p = rem & (HW - 1);
        const float* x = img ? x2 : x1;
        const float* col = x + (size_t)b * 48 * HW + p;
        float v[48]; float s = 0.f;
#pragma unroll
        for (int c = 0; c < 48; ++c) { v[c] = col[c * HW]; s = fmaf(v[c], v[c], s); }
        float r = 1.f / fmaxf(sqrtf(s), 1e-12f);
        unsigned short* dst = dbp + ((size_t)(img * BB + b) * HW + p) * KHW;
#pragma unroll
        for (int ch = 0; ch < 6; ++ch) {
            union { unsigned u[4]; floatx4 f; } pk;
#pragma unroll
            for (int d = 0; d < 4; ++d) {
                int c = ch * 8 + d * 2;
                pk.u[d] = (unsigned)f2bf(v[c] * r) | ((unsigned)f2bf(v[c + 1] * r) << 16);
            }
            *(floatx4*)(dst + ch * 8) = pk.f;
        }
        floatx4 z = {0.f, 0.f, 0.f, 0.f};
#pragma unroll
        for (int ch = 6; ch < 9; ++ch) *(floatx4*)(dst + ch * 8) = z;
    } else if (bid < 544) {
        int seg = bid - 512;                      // dir*16 + b
        int dir = seg >> 4, b = seg & 15;
        if (tid < 64) hist[tid] = 0;
        __syncthreads();
#pragma unroll
        for (int k = 0; k < 8; ++k) {
            int n = k * 256 + tid;
            int idv = ids[b * NC + n];
            int i2 = fp2[b * 2 * NC + n];
            int qi = (dir == 0) ? i2 : (idv >> 6);
            atomicAdd(&hist[qi], 1);
        }
        __syncthreads();
        if (tid == 0) {
            int run = 0;
            for (int k = 0; k < 64; ++k) { base[k] = run; run += hist[k]; }
        }
        __syncthreads();
#pragma unroll
        for (int k = 0; k < 8; ++k) {
            int n = k * 256 + tid;
            int idv = ids[b * NC + n];
            int i2 = fp2[b * 2 * NC + n];
            int j2 = fp2[b * 2 * NC + NC + n];
            int qi, qj, qcol;
            if (dir == 0) { qi = i2; qj = j2; qcol = idv; }
            else          { qi = idv >> 6; qj = idv & 63; qcol = i2 * 64 + j2; }
            int slot = atomicAdd(&base[qi], 1);
            perm[seg * NC + slot] = n;
            qcol_s[seg * NC + slot] = qcol;
            aqpack[seg * NC + slot] = (qi << 8) | qj;
        }
    } else {
        int t = (bid - 544) * 256 + tid;          // [0, 2048)
        uint4* p = (uint4*)maxs2enc;              // 16384 uint4 total
        uint4 z = {0u, 0u, 0u, 0u};
#pragma unroll
        for (int k = 0; k < 8; ++k) p[k * 2048 + t] = z;
    }
}

// ---------------------------------------------------------------------------
// maxscore_mfma: masked hardest-negative via MFMA, qi-sorted queries.
// grid = 2048: seg = gid&31, mtile = (gid>>5)&7, neighth = gid>>8.
// Per block: 256 sorted queries x 512 db cols; 8 double-buffered 64-col LDS
// tiles (one tile == one db row -> row mask hoisted per tile).
// LDS 18432 B -> 8 blocks/CU; VGPR<=64 via launch_bounds(256,8).
// ---------------------------------------------------------------------------
static __device__ __forceinline__ void dma64(const unsigned char* g, unsigned char* l,
                                             int wave, int lane) {
    int wo = wave * 2304;
#pragma unroll
    for (int rr = 0; rr < 2; ++rr)
        GLD16(g + wo + rr * 1024 + lane * 16, l + wo + rr * 1024);
    GLD4(g + wo + 2048 + lane * 4, l + wo + 2048);
}

__global__ __launch_bounds__(256, 8) void maxscore_mfma(
    const unsigned short* __restrict__ dbp,
    const int* __restrict__ perm, const int* __restrict__ qcol_s,
    const int* __restrict__ aqpack, unsigned int* __restrict__ maxs2enc) {
    __shared__ __align__(16) unsigned char smem[18432];   // 2 db buffers of 9216

    int tid = threadIdx.x, wave = tid >> 6, lane = tid & 63;
    int quad = lane >> 4, cl = lane & 15;
    int gid = blockIdx.x;
    int seg = gid & 31, dir = seg >> 4, b = seg & 15;
    int rest = gid >> 5, mtile = rest & 7, nq = rest >> 3;   // nq in [0,8)
    int qbase = mtile * 256;
    int dbimg = 1 - dir;

    // A-fragments: 16B gathers straight from dbp (query image = dir; L2-hot)
    const unsigned char* dbQ = (const unsigned char*)(dbp + (size_t)(dir * BB + b) * HW * KHW);
    short8 afr[4][2];
#pragma unroll
    for (int t = 0; t < 4; ++t) {
        int slot = qbase + wave * 64 + t * 16 + cl;       // A[m=lane&15]
        int qc = qcol_s[seg * NC + slot];
        const unsigned char* src = dbQ + (size_t)qc * KB;
        afr[t][0] = *(const short8*)(src + quad * 16);
        afr[t][1] = *(const short8*)(src + 64 + quad * 16);
    }
    // Anchors for this lane's C/D rows (row = quad*4+r)
    float qif[4][4], qjc[4][4];
    float cl_f = (float)cl;
#pragma unroll
    for (int t = 0; t < 4; ++t)
#pragma unroll
        for (int r = 0; r < 4; ++r) {
            int slot = qbase + wave * 64 + t * 16 + quad * 4 + r;
            int ap = aqpack[seg * NC + slot];
            qif[t][r] = (float)(ap >> 8);
            qjc[t][r] = (float)(ap & 255) - cl_f;         // qj - lane col offset
        }
    // Wave's sorted qi range
    int wb = seg * NC + qbase + wave * 64;
    int qimin = __builtin_amdgcn_readfirstlane(aqpack[wb] >> 8);
    int qimax = __builtin_amdgcn_readfirstlane(aqpack[wb + 63] >> 8);

    const unsigned char* dsrc =
        (const unsigned char*)(dbp + ((size_t)(dbimg * BB + b) * HW + nq * 512) * KHW);
    dma64(dsrc, smem, wave, lane);                        // prefetch tile 0

    const floatx4 zf = {0.f, 0.f, 0.f, 0.f};
    float mx[4][4];
#pragma unroll
    for (int t = 0; t < 4; ++t)
#pragma unroll
        for (int r = 0; r < 4; ++r) mx[t][r] = -1e30f;

    for (int tile = 0; tile < 8; ++tile) {
        unsigned char* buf = smem + (tile & 1) * 9216;
        __syncthreads();
        if (tile + 1 < 8)
            dma64(dsrc + (tile + 1) * 9216, smem + ((tile + 1) & 1) * 9216, wave, lane);
        int mi = nq * 8 + tile;                           // one db row per tile
        bool active = (mi >= qimin - 4) && (mi <= qimax + 4);   // wave-uniform
        if (active) {
            float mi_f = (float)mi;
            bool rowok[4][4];
#pragma unroll
            for (int t = 0; t < 4; ++t)
#pragma unroll
                for (int r = 0; r < 4; ++r)
                    rowok[t][r] = fabsf(qif[t][r] - mi_f) > 4.0f;
#pragma unroll
            for (int js = 0; js < 4; ++js) {
                float jj = (float)(js * 16);
                short8 b0 = *(const short8*)(buf + (js * 16 + cl) * KB + quad * 16);
                short8 b1 = *(const short8*)(buf + (js * 16 + cl) * KB + 64 + quad * 16);
#pragma unroll
                for (int t = 0; t < 4; ++t) {
                    floatx4 acc = __builtin_amdgcn_mfma_f32_16x16x32_bf16(
                        __builtin_bit_cast(bf16x8, afr[t][0]),
                        __builtin_bit_cast(bf16x8, b0), zf, 0, 0, 0);
                    acc = __builtin_amdgcn_mfma_f32_16x16x32_bf16(
                        __builtin_bit_cast(bf16x8, afr[t][1]),
                        __builtin_bit_cast(bf16x8, b1), acc, 0, 0, 0);
#pragma unroll
                    for (int r = 0; r < 4; ++r) {
                        float dj = qjc[t][r] - jj;
                        bool ok = rowok[t][r] || (fabsf(dj) > 4.0f);
                        mx[t][r] = ok ? fmaxf(mx[t][r], acc[r]) : mx[t][r];
                    }
                }
            }
        } else {                                          // all rows allowed: 1 op/elem
#pragma unroll
            for (int js = 0; js < 4; ++js) {
                short8 b0 = *(const short8*)(buf + (js * 16 + cl) * KB + quad * 16);
                short8 b1 = *(const short8*)(buf + (js * 16 + cl) * KB + 64 + quad * 16);
#pragma unroll
                for (int t = 0; t < 4; ++t) {
                    floatx4 acc = __builtin_amdgcn_mfma_f32_16x16x32_bf16(
                        __builtin_bit_cast(bf16x8, afr[t][0]),
                        __builtin_bit_cast(bf16x8, b0), zf, 0, 0, 0);
                    acc = __builtin_amdgcn_mfma_f32_16x16x32_bf16(
                        __builtin_bit_cast(bf16x8, afr[t][1]),
                        __builtin_bit_cast(bf16x8, b1), acc, 0, 0, 0);
#pragma unroll
                    for (int r = 0; r < 4; ++r)
                        mx[t][r] = fmaxf(mx[t][r], acc[r]);
                }
            }
        }
    }

    // reduce max over the 16 lanes of each quad (disjoint col subsets)
#pragma unroll
    for (int t = 0; t < 4; ++t)
#pragma unroll
        for (int r = 0; r < 4; ++r) {
            float v = mx[t][r];
            v = fmaxf(v, __shfl_xor(v, 1, 16));
            v = fmaxf(v, __shfl_xor(v, 2, 16));
            v = fmaxf(v, __shfl_xor(v, 4, 16));
            v = fmaxf(v, __shfl_xor(v, 8, 16));
            mx[t][r] = v;
        }
    if (cl == 0) {
#pragma unroll
        for (int t = 0; t < 4; ++t)
#pragma unroll
            for (int r = 0; r < 4; ++r) {
                int slot = qbase + wave * 64 + t * 16 + quad * 4 + r;
                int orig = perm[seg * NC + slot];
                float v = mx[t][r] + 2.0f;                // > 0: uint-monotone
                atomicMax(&maxs2enc[(size_t)seg * NC + orig],
                          __builtin_bit_cast(unsigned, v));
            }
    }
}

// ---------------------------------------------------------------------------
// loss: pos-distance from dbp bf16 columns (consistent rounding with neg
// path), decode/merge direction maxes, weighted partial sums. grid = 128.
// ---------------------------------------------------------------------------
__global__ void loss_kernel(const float* __restrict__ att1, const float* __restrict__ att2,
                            const int* __restrict__ ids, const int* __restrict__ fp2,
                            const unsigned short* __restrict__ dbp,
                            const unsigned int* __restrict__ maxs2enc,
                            float* __restrict__ pnum, float* __restrict__ pden) {
    int b = blockIdx.x >> 3, chunk = blockIdx.x & 7;
    int tid = threadIdx.x;
    int n = chunk * 256 + tid;
    int idv = ids[b * NC + n];
    int i2 = fp2[b * 2 * NC + n], j2 = fp2[b * 2 * NC + NC + n];
    const uint4* a4 = (const uint4*)(dbp + ((size_t)(0 * BB + b) * HW + idv) * KHW);
    const uint4* b4 = (const uint4*)(dbp + ((size_t)(1 * BB + b) * HW + i2 * 64 + j2) * KHW);
    float dot = 0.f;
#pragma unroll
    for (int i = 0; i < 6; ++i) {
        uint4 xa = a4[i], xb = b4[i];
        const unsigned* xu = (const unsigned*)&xa;
        const unsigned* yu = (const unsigned*)&xb;
#pragma unroll
        for (int w = 0; w < 4; ++w) {
            float xl = __builtin_bit_cast(float, xu[w] << 16);
            float xh = __builtin_bit_cast(float, xu[w] & 0xffff0000u);
            float yl = __builtin_bit_cast(float, yu[w] << 16);
            float yh = __builtin_bit_cast(float, yu[w] & 0xffff0000u);
            dot = fmaf(xl, yl, fmaf(xh, yh, dot));
        }
    }
    float m0 = __builtin_bit_cast(float, maxs2enc[(size_t)(0 * BB + b) * NC + n]) - 2.0f;
    float m1 = __builtin_bit_cast(float, maxs2enc[(size_t)(1 * BB + b) * NC + n]) - 2.0f;
    float ms = fmaxf(m0, m1);
    float diff = (2.f - 2.f * dot) - (2.f - 2.f * ms);
    float w = att1[b * HW + idv] * att2[b * HW + i2 * 64 + j2];
    float num = w * fmaxf(0.f, 1.f + diff);
    float den = w;
    __shared__ float sn[256], sd[256];
    sn[tid] = num; sd[tid] = den;
    __syncthreads();
    for (int s = 128; s > 0; s >>= 1) {
        if (tid < s) { sn[tid] += sn[tid + s]; sd[tid] += sd[tid + s]; }
        __syncthreads();
    }
    if (tid == 0) { pnum[blockIdx.x] = sn[0]; pden[blockIdx.x] = sd[0]; }
}

__global__ void final_kernel(const float* __restrict__ pnum, const float* __restrict__ pden,
                             float* __restrict__ out) {
    int tid = threadIdx.x;
    __shared__ float r[16];
    if (tid < 16) {
        float n = 0.f, d = 0.f;
#pragma unroll
        for (int c = 0; c < 8; ++c) { n += pnum[tid * 8 + c]; d += pden[tid * 8 + c]; }
        r[tid] = n / d;
    }
    __syncthreads();
    if (tid == 0) {
        float s = 0.f;
#pragma unroll
        for (int k = 0; k < 16; ++k) s += r[k];
        out[0] = s * (1.f / BB);
    }
}

extern "C" void kernel_launch(void* const* d_in, const int* in_sizes, int n_in,
                              void* d_out, int out_size, void* d_ws, size_t ws_size,
                              hipStream_t stream) {
    const float* x1  = (const float*)d_in[0];
    const float* x2  = (const float*)d_in[1];
    const float* att1 = (const float*)d_in[2];
    const float* att2 = (const float*)d_in[3];
    const int* ids   = (const int*)d_in[4];
    const int* fp2   = (const int*)d_in[5];
    float* out = (float*)d_out;

    // ws layout (bytes), total ~19.9 MB, fully rewritten every call:
    unsigned char* w = (unsigned char*)d_ws;
    unsigned short* dbp = (unsigned short*)(w + 0);          // 2*16*4096*144 = 18,874,368
    int* perm    = (int*)(w + 18874368);                     // 32*2048*4 = 262,144
    int* qcol_s  = (int*)(w + 19136512);                     // 262,144
    int* aqpack  = (int*)(w + 19398656);                     // 262,144
    unsigned int* maxs2enc = (unsigned int*)(w + 19660800);  // 262,144
    float* pnum  = (float*)(w + 19922944);                   // 512
    float* pden  = (float*)(w + 19923456);                   // 512

    prep_fused<<<dim3(552), dim3(256), 0, stream>>>(x1, x2, ids, fp2, dbp,
                                                    perm, qcol_s, aqpack, maxs2enc);
    maxscore_mfma<<<dim3(2048), dim3(256), 0, stream>>>(dbp, perm, qcol_s, aqpack, maxs2enc);
    loss_kernel<<<dim3(128), dim3(256), 0, stream>>>(att1, att2, ids, fp2, dbp, maxs2enc, pnum, pden);
    final_kernel<<<dim3(1), dim3(64), 0, stream>>>(pnum, pden, out);
}

// Round 5
// 144.510 us; speedup vs baseline: 2.9833x; 2.9833x over previous
//
#include <hip/hip_runtime.h>
#include <stdint.h>

// Problem constants: B=16, C=48, H=W=64, N_CORR=2048
#define BB 16
#define HW 4096
#define NC 2048
#define KHW 72           // halfwords per column: 48 data + 16 zeros (K-pad to 64) + 8 pad
#define KB 144           // bytes per column (16B-aligned)

typedef __attribute__((ext_vector_type(8))) __bf16 bf16x8;
typedef __attribute__((ext_vector_type(8))) short short8;
typedef __attribute__((ext_vector_type(4))) float floatx4;

static __device__ __forceinline__ unsigned short f2bf(float f) {
    unsigned u = __builtin_bit_cast(unsigned, f);
    unsigned r = u + 0x7fffu + ((u >> 16) & 1u);    // RNE
    return (unsigned short)(r >> 16);
}

#define GLD16(g, l) __builtin_amdgcn_global_load_lds((const __attribute__((address_space(1))) void*)(g), (__attribute__((address_space(3))) void*)(l), 16, 0, 0)
#define GLD4(g, l)  __builtin_amdgcn_global_load_lds((const __attribute__((address_space(1))) void*)(g), (__attribute__((address_space(3))) void*)(l), 4, 0, 0)

// ---------------------------------------------------------------------------
// prep_fused: three independent jobs in one launch:
//   blocks [0,512):   normalize x1,x2 columns -> bf16 dbp. Output slab staged
//                     in LDS, then written COALESCED (R4 post-mortem: direct
//                     144B-stride lane writes cost ~16x line-transactions).
//   blocks [512,544): counting sort of each (dir,b) query segment by qi
//   blocks [544,552): zero maxs2enc (atomicMax identity)
// ---------------------------------------------------------------------------
__global__ void prep_fused(const float* __restrict__ x1, const float* __restrict__ x2,
                           const int* __restrict__ ids, const int* __restrict__ fp2,
                           unsigned short* __restrict__ dbp,
                           int* __restrict__ perm, int* __restrict__ qcol_s,
                           int* __restrict__ aqpack, unsigned int* __restrict__ maxs2enc) {
    __shared__ __align__(16) unsigned char slab[36864];   // 256 cols x 144 B
    int bid = blockIdx.x, tid = threadIdx.x;
    if (bid < 512) {
        // whole block = one (img,b); p spans a 256-aligned range
        int img = bid >> 8;
        int b = (bid & 255) >> 4;
        int p0 = (bid & 15) * 256;
        int p = p0 + tid;
        const float* x = img ? x2 : x1;
        const float* col = x + (size_t)b * 48 * HW + p;
        float v[48]; float s = 0.f;
#pragma unroll
        for (int c = 0; c < 48; ++c) { v[c] = col[c * HW]; s = fmaf(v[c], v[c], s); }
        float r = 1.f / fmaxf(sqrtf(s), 1e-12f);
        unsigned short* lcol = (unsigned short*)(slab + tid * KB);
#pragma unroll
        for (int ch = 0; ch < 6; ++ch) {
            union { unsigned u[4]; floatx4 f; } pk;
#pragma unroll
            for (int d = 0; d < 4; ++d) {
                int c = ch * 8 + d * 2;
                pk.u[d] = (unsigned)f2bf(v[c] * r) | ((unsigned)f2bf(v[c + 1] * r) << 16);
            }
            *(floatx4*)(lcol + ch * 8) = pk.f;
        }
        floatx4 z = {0.f, 0.f, 0.f, 0.f};
#pragma unroll
        for (int ch = 6; ch < 9; ++ch) *(floatx4*)(lcol + ch * 8) = z;
        __syncthreads();
        // coalesced copy-out: 9 rounds x 256 threads x 16 B contiguous
        unsigned char* dstb = (unsigned char*)dbp + ((size_t)(img * BB + b) * HW + p0) * KB;
#pragma unroll
        for (int rr = 0; rr < 9; ++rr) {
            int idx = rr * 4096 + tid * 16;
            *(floatx4*)(dstb + idx) = *(const floatx4*)(slab + idx);
        }
    } else if (bid < 544) {
        int* hist = (int*)slab;
        int* base = hist + 64;
        int seg = bid - 512;                      // dir*16 + b
        int dir = seg >> 4, b = seg & 15;
        if (tid < 64) hist[tid] = 0;
        __syncthreads();
#pragma unroll
        for (int k = 0; k < 8; ++k) {
            int n = k * 256 + tid;
            int idv = ids[b * NC + n];
            int i2 = fp2[b * 2 * NC + n];
            int qi = (dir == 0) ? i2 : (idv >> 6);
            atomicAdd(&hist[qi], 1);
        }
        __syncthreads();
        if (tid == 0) {
            int run = 0;
            for (int k = 0; k < 64; ++k) { base[k] = run; run += hist[k]; }
        }
        __syncthreads();
#pragma unroll
        for (int k = 0; k < 8; ++k) {
            int n = k * 256 + tid;
            int idv = ids[b * NC + n];
            int i2 = fp2[b * 2 * NC + n];
            int j2 = fp2[b * 2 * NC + NC + n];
            int qi, qj, qcol;
            if (dir == 0) { qi = i2; qj = j2; qcol = idv; }
            else          { qi = idv >> 6; qj = idv & 63; qcol = i2 * 64 + j2; }
            int slot = atomicAdd(&base[qi], 1);
            perm[seg * NC + slot] = n;
            qcol_s[seg * NC + slot] = qcol;
            aqpack[seg * NC + slot] = (qi << 8) | qj;
        }
    } else {
        int t = (bid - 544) * 256 + tid;          // [0, 2048)
        uint4* p = (uint4*)maxs2enc;              // 16384 uint4 total
        uint4 z = {0u, 0u, 0u, 0u};
#pragma unroll
        for (int k = 0; k < 8; ++k) p[k * 2048 + t] = z;
    }
}

// ---------------------------------------------------------------------------
// maxscore_mfma: masked hardest-negative via MFMA, qi-sorted queries.
// grid = 2048: seg = gid&31, mtile = (gid>>5)&7, neighth = gid>>8.
// Per block: 256 sorted queries x 512 db cols; 8 double-buffered 64-col LDS
// tiles (one tile == one db row). M=256/block keeps MFMA:ds_read at 4:1.
// Anchors packed 2-per-int; row mask folded into qjd sentinel (blocked row ->
// qjd=1e6 so the j-test always passes) => active epilogue 3 VALU/elem with
// only 16 branch-local temps. NO min-waves clause (R4: forcing 8 spilled).
// ---------------------------------------------------------------------------
static __device__ __forceinline__ void dma64(const unsigned char* g, unsigned char* l,
                                             int wave, int lane) {
    int wo = wave * 2304;
#pragma unroll
    for (int rr = 0; rr < 2; ++rr)
        GLD16(g + wo + rr * 1024 + lane * 16, l + wo + rr * 1024);
    GLD4(g + wo + 2048 + lane * 4, l + wo + 2048);
}

__global__ __launch_bounds__(256) void maxscore_mfma(
    const unsigned short* __restrict__ dbp,
    const int* __restrict__ perm, const int* __restrict__ qcol_s,
    const int* __restrict__ aqpack, unsigned int* __restrict__ maxs2enc) {
    __shared__ __align__(16) unsigned char smem[18432];   // 2 db buffers of 9216

    int tid = threadIdx.x, wave = tid >> 6, lane = tid & 63;
    int quad = lane >> 4, cl = lane & 15;
    int gid = blockIdx.x;
    int seg = gid & 31, dir = seg >> 4, b = seg & 15;
    int rest = gid >> 5, mtile = rest & 7, nq = rest >> 3;   // nq in [0,8)
    int qbase = mtile * 256;
    int dbimg = 1 - dir;

    // A-fragments: 16B gathers straight from dbp (query image = dir; L2-hot)
    const unsigned char* dbQ = (const unsigned char*)(dbp + (size_t)(dir * BB + b) * HW * KHW);
    short8 afr[4][2];
#pragma unroll
    for (int t = 0; t < 4; ++t) {
        int slot = qbase + wave * 64 + t * 16 + cl;       // A[m=lane&15]
        int qc = qcol_s[seg * NC + slot];
        const unsigned char* src = dbQ + (size_t)qc * KB;
        afr[t][0] = *(const short8*)(src + quad * 16);
        afr[t][1] = *(const short8*)(src + 64 + quad * 16);
    }
    // Anchors for this lane's C/D rows (row = quad*4+r), packed 2 per int
    int aqp2[4][2];
#pragma unroll
    for (int t = 0; t < 4; ++t)
#pragma unroll
        for (int pp = 0; pp < 2; ++pp) {
            int s0 = seg * NC + qbase + wave * 64 + t * 16 + quad * 4 + pp * 2;
            aqp2[t][pp] = aqpack[s0] | (aqpack[s0 + 1] << 16);
        }
    // Wave's sorted qi range
    int wb = seg * NC + qbase + wave * 64;
    int qimin = __builtin_amdgcn_readfirstlane(aqpack[wb] >> 8);
    int qimax = __builtin_amdgcn_readfirstlane(aqpack[wb + 63] >> 8);

    const unsigned char* dsrc =
        (const unsigned char*)(dbp + ((size_t)(dbimg * BB + b) * HW + nq * 512) * KHW);
    dma64(dsrc, smem, wave, lane);                        // prefetch tile 0

    const floatx4 zf = {0.f, 0.f, 0.f, 0.f};
    float cl_f = (float)cl;
    float mx[4][4];
#pragma unroll
    for (int t = 0; t < 4; ++t)
#pragma unroll
        for (int r = 0; r < 4; ++r) mx[t][r] = -1e30f;

    for (int tile = 0; tile < 8; ++tile) {
        unsigned char* buf = smem + (tile & 1) * 9216;
        __syncthreads();
        if (tile + 1 < 8)
            dma64(dsrc + (tile + 1) * 9216, smem + ((tile + 1) & 1) * 9216, wave, lane);
        int mi = nq * 8 + tile;                           // one db row per tile
        bool active = (mi >= qimin - 4) && (mi <= qimax + 4);   // wave-uniform
        if (active) {
            float mi_f = (float)mi;
            float qjd[4][4];                              // sentinel-folded anchors
#pragma unroll
            for (int t = 0; t < 4; ++t)
#pragma unroll
                for (int r = 0; r < 4; ++r) {
                    int ap = (aqp2[t][r >> 1] >> (16 * (r & 1))) & 0xffff;
                    bool rowblk = fabsf((float)(ap >> 8) - mi_f) <= 4.0f;
                    qjd[t][r] = rowblk ? ((float)(ap & 255) - cl_f) : 1e6f;
                }
#pragma unroll
            for (int js = 0; js < 4; ++js) {
                float jj = (float)(js * 16);
                short8 b0 = *(const short8*)(buf + (js * 16 + cl) * KB + quad * 16);
                short8 b1 = *(const short8*)(buf + (js * 16 + cl) * KB + 64 + quad * 16);
#pragma unroll
                for (int t = 0; t < 4; ++t) {
                    floatx4 acc = __builtin_amdgcn_mfma_f32_16x16x32_bf16(
                        __builtin_bit_cast(bf16x8, afr[t][0]),
                        __builtin_bit_cast(bf16x8, b0), zf, 0, 0, 0);
                    acc = __builtin_amdgcn_mfma_f32_16x16x32_bf16(
                        __builtin_bit_cast(bf16x8, afr[t][1]),
                        __builtin_bit_cast(bf16x8, b1), acc, 0, 0, 0);
#pragma unroll
                    for (int r = 0; r < 4; ++r) {
                        bool ok = fabsf(qjd[t][r] - jj) > 4.0f;
                        mx[t][r] = ok ? fmaxf(mx[t][r], acc[r]) : mx[t][r];
                    }
                }
            }
        } else {                                          // all rows allowed: 1 op/elem
#pragma unroll
            for (int js = 0; js < 4; ++js) {
                short8 b0 = *(const short8*)(buf + (js * 16 + cl) * KB + quad * 16);
                short8 b1 = *(const short8*)(buf + (js * 16 + cl) * KB + 64 + quad * 16);
#pragma unroll
                for (int t = 0; t < 4; ++t) {
                    floatx4 acc = __builtin_amdgcn_mfma_f32_16x16x32_bf16(
                        __builtin_bit_cast(bf16x8, afr[t][0]),
                        __builtin_bit_cast(bf16x8, b0), zf, 0, 0, 0);
                    acc = __builtin_amdgcn_mfma_f32_16x16x32_bf16(
                        __builtin_bit_cast(bf16x8, afr[t][1]),
                        __builtin_bit_cast(bf16x8, b1), acc, 0, 0, 0);
#pragma unroll
                    for (int r = 0; r < 4; ++r)
                        mx[t][r] = fmaxf(mx[t][r], acc[r]);
                }
            }
        }
    }

    // reduce max over the 16 lanes of each quad (disjoint col subsets)
#pragma unroll
    for (int t = 0; t < 4; ++t)
#pragma unroll
        for (int r = 0; r < 4; ++r) {
            float v = mx[t][r];
            v = fmaxf(v, __shfl_xor(v, 1, 16));
            v = fmaxf(v, __shfl_xor(v, 2, 16));
            v = fmaxf(v, __shfl_xor(v, 4, 16));
            v = fmaxf(v, __shfl_xor(v, 8, 16));
            mx[t][r] = v;
        }
    if (cl == 0) {
#pragma unroll
        for (int t = 0; t < 4; ++t)
#pragma unroll
            for (int r = 0; r < 4; ++r) {
                int slot = qbase + wave * 64 + t * 16 + quad * 4 + r;
                int orig = perm[seg * NC + slot];
                float v = mx[t][r] + 2.0f;                // > 0: uint-monotone
                atomicMax(&maxs2enc[(size_t)seg * NC + orig],
                          __builtin_bit_cast(unsigned, v));
            }
    }
}

// ---------------------------------------------------------------------------
// loss: pos-distance from dbp bf16 columns (consistent rounding with neg
// path), decode/merge direction maxes, weighted partial sums. grid = 128.
// ---------------------------------------------------------------------------
__global__ void loss_kernel(const float* __restrict__ att1, const float* __restrict__ att2,
                            const int* __restrict__ ids, const int* __restrict__ fp2,
                            const unsigned short* __restrict__ dbp,
                            const unsigned int* __restrict__ maxs2enc,
                            float* __restrict__ pnum, float* __restrict__ pden) {
    int b = blockIdx.x >> 3, chunk = blockIdx.x & 7;
    int tid = threadIdx.x;
    int n = chunk * 256 + tid;
    int idv = ids[b * NC + n];
    int i2 = fp2[b * 2 * NC + n], j2 = fp2[b * 2 * NC + NC + n];
    const uint4* a4 = (const uint4*)(dbp + ((size_t)(0 * BB + b) * HW + idv) * KHW);
    const uint4* b4 = (const uint4*)(dbp + ((size_t)(1 * BB + b) * HW + i2 * 64 + j2) * KHW);
    float dot = 0.f;
#pragma unroll
    for (int i = 0; i < 6; ++i) {
        uint4 xa = a4[i], xb = b4[i];
        const unsigned* xu = (const unsigned*)&xa;
        const unsigned* yu = (const unsigned*)&xb;
#pragma unroll
        for (int w = 0; w < 4; ++w) {
            float xl = __builtin_bit_cast(float, xu[w] << 16);
            float xh = __builtin_bit_cast(float, xu[w] & 0xffff0000u);
            float yl = __builtin_bit_cast(float, yu[w] << 16);
            float yh = __builtin_bit_cast(float, yu[w] & 0xffff0000u);
            dot = fmaf(xl, yl, fmaf(xh, yh, dot));
        }
    }
    float m0 = __builtin_bit_cast(float, maxs2enc[(size_t)(0 * BB + b) * NC + n]) - 2.0f;
    float m1 = __builtin_bit_cast(float, maxs2enc[(size_t)(1 * BB + b) * NC + n]) - 2.0f;
    float ms = fmaxf(m0, m1);
    float diff = (2.f - 2.f * dot) - (2.f - 2.f * ms);
    float w = att1[b * HW + idv] * att2[b * HW + i2 * 64 + j2];
    float num = w * fmaxf(0.f, 1.f + diff);
    float den = w;
    __shared__ float sn[256], sd[256];
    sn[tid] = num; sd[tid] = den;
    __syncthreads();
    for (int s = 128; s > 0; s >>= 1) {
        if (tid < s) { sn[tid] += sn[tid + s]; sd[tid] += sd[tid + s]; }
        __syncthreads();
    }
    if (tid == 0) { pnum[blockIdx.x] = sn[0]; pden[blockIdx.x] = sd[0]; }
}

__global__ void final_kernel(const float* __restrict__ pnum, const float* __restrict__ pden,
                             float* __restrict__ out) {
    int tid = threadIdx.x;
    __shared__ float r[16];
    if (tid < 16) {
        float n = 0.f, d = 0.f;
#pragma unroll
        for (int c = 0; c < 8; ++c) { n += pnum[tid * 8 + c]; d += pden[tid * 8 + c]; }
        r[tid] = n / d;
    }
    __syncthreads();
    if (tid == 0) {
        float s = 0.f;
#pragma unroll
        for (int k = 0; k < 16; ++k) s += r[k];
        out[0] = s * (1.f / BB);
    }
}

extern "C" void kernel_launch(void* const* d_in, const int* in_sizes, int n_in,
                              void* d_out, int out_size, void* d_ws, size_t ws_size,
                              hipStream_t stream) {
    const float* x1  = (const float*)d_in[0];
    const float* x2  = (const float*)d_in[1];
    const float* att1 = (const float*)d_in[2];
    const float* att2 = (const float*)d_in[3];
    const int* ids   = (const int*)d_in[4];
    const int* fp2   = (const int*)d_in[5];
    float* out = (float*)d_out;

    // ws layout (bytes), total ~19.9 MB, fully rewritten every call:
    unsigned char* w = (unsigned char*)d_ws;
    unsigned short* dbp = (unsigned short*)(w + 0);          // 2*16*4096*144 = 18,874,368
    int* perm    = (int*)(w + 18874368);                     // 32*2048*4 = 262,144
    int* qcol_s  = (int*)(w + 19136512);                     // 262,144
    int* aqpack  = (int*)(w + 19398656);                     // 262,144
    unsigned int* maxs2enc = (unsigned int*)(w + 19660800);  // 262,144
    float* pnum  = (float*)(w + 19922944);                   // 512
    float* pden  = (float*)(w + 19923456);                   // 512

    prep_fused<<<dim3(552), dim3(256), 0, stream>>>(x1, x2, ids, fp2, dbp,
                                                    perm, qcol_s, aqpack, maxs2enc);
    maxscore_mfma<<<dim3(2048), dim3(256), 0, stream>>>(dbp, perm, qcol_s, aqpack, maxs2enc);
    loss_kernel<<<dim3(128), dim3(256), 0, stream>>>(att1, att2, ids, fp2, dbp, maxs2enc, pnum, pden);
    final_kernel<<<dim3(1), dim3(64), 0, stream>>>(pnum, pden, out);
}